// Round 1
// baseline (166.687 us; speedup 1.0000x reference)
//
#include <hip/hip_runtime.h>
#include <cmath>

// Problem constants
#define S_SEQ 4096
#define N_GATES 3072          // 3*H
#define N1 6144               // GEMM1 N (P | Q)
#define K1 1024               // GEMM1 K (= D)
#define NCH 64                // scan chunks
#define CHR 64                // rows per chunk (NCH*CHR = 4096)

typedef _Float16 half8_t __attribute__((ext_vector_type(8)));
typedef _Float16 half4_t __attribute__((ext_vector_type(4)));
typedef float f32x4_t __attribute__((ext_vector_type(4)));

__device__ __forceinline__ void gload_lds16(const void* g, void* l) {
  __builtin_amdgcn_global_load_lds(
      (const __attribute__((address_space(1))) void*)g,
      (__attribute__((address_space(3))) void*)l, 16, 0, 0);
}

// ---------------- conversion kernels ----------------
__global__ void conv_f32_f16(const float* __restrict__ src,
                             _Float16* __restrict__ dst, int n4) {
  int i = blockIdx.x * 256 + threadIdx.x;
  if (i >= n4) return;
  float4 v = *(const float4*)(src + (size_t)i * 4);
  half4_t h;
  h[0] = (_Float16)v.x; h[1] = (_Float16)v.y;
  h[2] = (_Float16)v.z; h[3] = (_Float16)v.w;
  *(half4_t*)(dst + (size_t)i * 4) = h;
}

// W1 [3072][2048] row-major -> [6144][1024] with rows [0..3072)=W1a, [3072..6144)=W1b
__global__ void conv_w1(const float* __restrict__ W1, _Float16* __restrict__ dst) {
  int i = blockIdx.x * 256 + threadIdx.x;     // one float4 each
  if (i >= N1 * (K1 / 4)) return;
  int n = i >> 8;                              // 256 vec4 per out row
  int kv = (i & 255) << 2;
  size_t src = (n < N_GATES) ? ((size_t)n * 2048 + kv)
                             : ((size_t)(n - N_GATES) * 2048 + 1024 + kv);
  float4 v = *(const float4*)(W1 + src);
  half4_t h;
  h[0] = (_Float16)v.x; h[1] = (_Float16)v.y;
  h[2] = (_Float16)v.z; h[3] = (_Float16)v.w;
  *(half4_t*)(dst + (size_t)n * K1 + kv) = h;
}

// ---------------- GEMM: C[M,N] = A[M,K] @ B[N,K]^T  (fp16 in, f32 acc) -----
// MODE 0: store f32 C (ld = N)
// MODE 1: out[idx] = (acc + bias[col]) * mul[idx]
template <int MODE>
__global__ __launch_bounds__(256, 2)
void gemm_bt(const _Float16* __restrict__ A, const _Float16* __restrict__ B,
             float* __restrict__ C, const float* __restrict__ bias,
             const float* __restrict__ mul, float* __restrict__ out,
             int M, int N, int K) {
  __shared__ _Float16 As[128 * 32];
  __shared__ _Float16 Bs[128 * 32];

  const int tid = threadIdx.x;
  const int lane = tid & 63;
  const int wid = tid >> 6;        // 0..3
  const int wr = wid >> 1;         // wave row (0..1)
  const int wc = wid & 1;          // wave col (0..1)

  const int m0 = blockIdx.y * 128;
  const int n0 = blockIdx.x * 128;

  const int srow = lane >> 2;            // 0..15
  const int scol = (lane & 3) << 3;      // 0,8,16,24 (half units)

  const _Float16* gA = A + (size_t)(m0 + wid * 32 + srow) * K + scol;
  const _Float16* gB = B + (size_t)(n0 + wid * 32 + srow) * K + scol;
  _Float16* lA = As + (wid * 32) * 32;
  _Float16* lB = Bs + (wid * 32) * 32;

  f32x4_t acc[4][4] = {};

  const int fr = lane & 15;
  const int fk = (lane >> 4) << 3;

  for (int kk = 0; kk < K; kk += 32) {
    gload_lds16(gA + kk,                lA);
    gload_lds16(gA + kk + (size_t)16*K, lA + 16 * 32);
    gload_lds16(gB + kk,                lB);
    gload_lds16(gB + kk + (size_t)16*K, lB + 16 * 32);
    __syncthreads();   // compiler emits vmcnt(0) drain before barrier

    half8_t af[4], bf[4];
#pragma unroll
    for (int m = 0; m < 4; ++m)
      af[m] = *(const half8_t*)&As[(wr * 64 + m * 16 + fr) * 32 + fk];
#pragma unroll
    for (int n = 0; n < 4; ++n)
      bf[n] = *(const half8_t*)&Bs[(wc * 64 + n * 16 + fr) * 32 + fk];
#pragma unroll
    for (int m = 0; m < 4; ++m)
#pragma unroll
      for (int n = 0; n < 4; ++n)
        acc[m][n] = __builtin_amdgcn_mfma_f32_16x16x32_f16(af[m], bf[n],
                                                           acc[m][n], 0, 0, 0);
    __syncthreads();   // protect LDS before next stage
  }

  const int crow = m0 + wr * 64 + ((lane >> 4) << 2);
  const int ccol = n0 + wc * 64 + (lane & 15);
#pragma unroll
  for (int m = 0; m < 4; ++m)
#pragma unroll
    for (int n = 0; n < 4; ++n) {
      int col = ccol + n * 16;
#pragma unroll
      for (int r = 0; r < 4; ++r) {
        size_t idx = (size_t)(crow + m * 16 + r) * N + col;
        if (MODE == 0) {
          C[idx] = acc[m][n][r];
        } else {
          float v = acc[m][n][r] + bias[col];
          out[idx] = v * mul[idx];
        }
      }
    }
}

// ---------------- scan over Q (gates = P + cumsum_excl(Q) + b1) ------------
// C layout: [4096][6144] f32, cols [0,3072)=P, [3072,6144)=Q
__global__ void scanA(const float* __restrict__ C, float* __restrict__ part) {
  int j = blockIdx.x * 256 + threadIdx.x;   // 0..3071
  int t0 = blockIdx.y * CHR;
  float s = 0.f;
  for (int t = t0; t < t0 + CHR; ++t)
    s += C[(size_t)t * N1 + N_GATES + j];
  part[blockIdx.y * N_GATES + j] = s;
}

__global__ void scanB(float* __restrict__ part) {
  int j = blockIdx.x * 256 + threadIdx.x;
  float run = 0.f;
  for (int c = 0; c < NCH; ++c) {
    float v = part[(size_t)c * N_GATES + j];
    part[(size_t)c * N_GATES + j] = run;
    run += v;
  }
}

__global__ void scanC(const float* __restrict__ C, const float* __restrict__ part,
                      const float* __restrict__ b1, float* __restrict__ igb,
                      _Float16* __restrict__ th, float* __restrict__ fg_out) {
  int j = blockIdx.x * 256 + threadIdx.x;   // gate column 0..3071
  int t0 = blockIdx.y * CHR;
  float run = part[blockIdx.y * N_GATES + j] + b1[j];
  if (j < 1024) {                      // ig
    for (int t = t0; t < t0 + CHR; ++t) {
      float g = C[(size_t)t * N1 + j] + run;
      run += C[(size_t)t * N1 + N_GATES + j];
      igb[(size_t)t * 1024 + j] = 1.f / (1.f + __expf(-g));
    }
  } else if (j < 2048) {               // fg -> output 0
    int jj = j - 1024;
    for (int t = t0; t < t0 + CHR; ++t) {
      float g = C[(size_t)t * N1 + j] + run;
      run += C[(size_t)t * N1 + N_GATES + j];
      fg_out[(size_t)t * 1024 + jj] = 1.f / (1.f + __expf(-g));
    }
  } else {                             // h -> tanh, fp16 for GEMM2
    int jj = j - 2048;
    for (int t = t0; t < t0 + CHR; ++t) {
      float g = C[(size_t)t * N1 + j] + run;
      run += C[(size_t)t * N1 + N_GATES + j];
      th[(size_t)t * 1024 + jj] = (_Float16)tanhf(g);
    }
  }
}

// ---------------- launch ----------------
extern "C" void kernel_launch(void* const* d_in, const int* in_sizes, int n_in,
                              void* d_out, int out_size, void* d_ws, size_t ws_size,
                              hipStream_t stream) {
  const float* x  = (const float*)d_in[0];
  const float* W1 = (const float*)d_in[1];
  const float* b1 = (const float*)d_in[2];
  const float* W2 = (const float*)d_in[3];
  const float* b2 = (const float*)d_in[4];
  float* out = (float*)d_out;

  char* ws = (char*)d_ws;
  _Float16* xh  = (_Float16*)(ws);                          //  8 MiB
  _Float16* w1h = (_Float16*)(ws + ((size_t)8  << 20));     // 12 MiB
  _Float16* w2h = (_Float16*)(ws + ((size_t)20 << 20));     //  2 MiB
  float*    C   = (float*)   (ws + ((size_t)22 << 20));     // 96 MiB
  float*    part= (float*)   (ws + ((size_t)118 << 20));    // .75 MiB
  float*    igb = (float*)   (ws + ((size_t)119 << 20));    // 16 MiB
  _Float16* th  = (_Float16*)(ws + ((size_t)135 << 20));    //  8 MiB

  conv_f32_f16<<<dim3(4096), dim3(256), 0, stream>>>(x, xh, S_SEQ * K1 / 4);
  conv_w1<<<dim3(6144), dim3(256), 0, stream>>>(W1, w1h);
  conv_f32_f16<<<dim3(1024), dim3(256), 0, stream>>>(W2, w2h, 1024 * 1024 / 4);

  // GEMM1: [4096,6144] = xh[4096,1024] @ w1h[6144,1024]^T
  gemm_bt<0><<<dim3(N1 / 128, S_SEQ / 128), dim3(256), 0, stream>>>(
      xh, w1h, C, nullptr, nullptr, nullptr, S_SEQ, N1, K1);

  scanA<<<dim3(N_GATES / 256, NCH), dim3(256), 0, stream>>>(C, part);
  scanB<<<dim3(N_GATES / 256), dim3(256), 0, stream>>>(part);
  scanC<<<dim3(N_GATES / 256, NCH), dim3(256), 0, stream>>>(C, part, b1, igb, th, out);

  // GEMM2: hr = (tanh(h) @ W2^T + b2) * ig  -> output 1
  gemm_bt<1><<<dim3(1024 / 128, S_SEQ / 128), dim3(256), 0, stream>>>(
      th, w2h, nullptr, b2, igb, out + (size_t)S_SEQ * 1024, S_SEQ, 1024, 1024);
}

// Round 2
// 153.873 us; speedup vs baseline: 1.0833x; 1.0833x over previous
//
#include <hip/hip_runtime.h>
#include <cmath>

#define S_SEQ 4096
#define HD 1024
#define NG 3072           // 3*H
#define CHR 32            // rows per scan chunk
#define NCH 128           // chunks (CHR*NCH = 4096)

typedef _Float16 half8_t __attribute__((ext_vector_type(8)));
typedef _Float16 half4_t __attribute__((ext_vector_type(4)));
typedef float f32x4_t __attribute__((ext_vector_type(4)));

__device__ __forceinline__ void gload_lds16(const void* g, void* l) {
  __builtin_amdgcn_global_load_lds(
      (const __attribute__((address_space(1))) void*)g,
      (__attribute__((address_space(3))) void*)l, 16, 0, 0);
}

__device__ __forceinline__ float sigmoidf_(float x) {
  return 1.f / (1.f + __expf(-x));
}
__device__ __forceinline__ float tanhf_(float x) {
  // saturates correctly: exp(+inf)->inf -> 1 ; exp(-inf)->0 -> -1
  return 1.f - 2.f / (__expf(2.f * x) + 1.f);
}

// ---------------- flat f32 -> fp16 conversion ----------------
__global__ void conv_f32_f16(const float* __restrict__ src,
                             _Float16* __restrict__ dst, int n4) {
  int i = blockIdx.x * 256 + threadIdx.x;
  if (i >= n4) return;
  float4 v = *(const float4*)(src + (size_t)i * 4);
  half4_t h;
  h[0] = (_Float16)v.x; h[1] = (_Float16)v.y;
  h[2] = (_Float16)v.z; h[3] = (_Float16)v.w;
  *(half4_t*)(dst + (size_t)i * 4) = h;
}

// ---------------- scan_x: A=[x | s_local] fp16, xsum=chunk sums fp16 -------
__global__ void scan_x(const float* __restrict__ x, _Float16* __restrict__ A,
                       _Float16* __restrict__ xsum) {
  int j = blockIdx.x * 256 + threadIdx.x;   // column 0..1023
  int c = blockIdx.y;                        // chunk 0..127
  int t0 = c * CHR;
  float run = 0.f;
  for (int t = t0; t < t0 + CHR; ++t) {
    float v = x[(size_t)t * HD + j];
    A[(size_t)t * 2048 + j]        = (_Float16)v;    // x part
    A[(size_t)t * 2048 + 1024 + j] = (_Float16)run;  // exclusive local cumsum
    run += v;
  }
  xsum[(size_t)c * HD + j] = (_Float16)run;
}

// ---------------- exclusive scan over chunk partials + b1 fold -------------
__global__ void scan_part(const float* __restrict__ praw,
                          const float* __restrict__ b1,
                          float* __restrict__ pout) {
  int j = blockIdx.x * 256 + threadIdx.x;   // 0..3071
  float run = b1[j];
  for (int c = 0; c < NCH; ++c) {
    float v = praw[(size_t)c * NG + j];
    pout[(size_t)c * NG + j] = run;
    run += v;
  }
}

// ---------------- GEMM: [M,N] = A[M,K] @ B[N,K-strided ldb]^T --------------
// MODE 0: C[row*N+col] = acc                                (part GEMM)
// MODE 1: out[idx] = (acc + bias[col]) * (float)mulh[idx]   (GEMM2 -> hr)
// MODE 2: g = acc + part[(row>>5)*NG + col]; gate epilogue  (GEMM1)
template <int MODE>
__global__ __launch_bounds__(256, 2)
void gemm_bt(const _Float16* __restrict__ A, const _Float16* __restrict__ B,
             int M, int N, int K, int ldb,
             float* __restrict__ C,
             const float* __restrict__ bias, const _Float16* __restrict__ mulh,
             float* __restrict__ out,
             const float* __restrict__ part, _Float16* __restrict__ igb,
             _Float16* __restrict__ th) {
  __shared__ _Float16 As[128 * 32];
  __shared__ _Float16 Bs[128 * 32];

  const int tid = threadIdx.x;
  const int lane = tid & 63;
  const int wid = tid >> 6;        // 0..3
  const int wr = wid >> 1;         // wave row (0..1)
  const int wc = wid & 1;          // wave col (0..1)

  const int m0 = blockIdx.y * 128;
  const int n0 = blockIdx.x * 128;

  const int srow = lane >> 2;            // 0..15
  const int scol = (lane & 3) << 3;      // 0,8,16,24 (halfs)

  const _Float16* gA = A + (size_t)(m0 + wid * 32 + srow) * K + scol;
  const _Float16* gB = B + (size_t)(n0 + wid * 32 + srow) * ldb + scol;
  _Float16* lA = As + (wid * 32) * 32;
  _Float16* lB = Bs + (wid * 32) * 32;

  f32x4_t acc[4][4] = {};

  const int fr = lane & 15;
  const int fk = (lane >> 4) << 3;

  for (int kk = 0; kk < K; kk += 32) {
    gload_lds16(gA + kk,                  lA);
    gload_lds16(gA + kk + (size_t)16*K,   lA + 16 * 32);
    gload_lds16(gB + kk,                  lB);
    gload_lds16(gB + kk + (size_t)16*ldb, lB + 16 * 32);
    __syncthreads();

    half8_t af[4], bf[4];
#pragma unroll
    for (int m = 0; m < 4; ++m)
      af[m] = *(const half8_t*)&As[(wr * 64 + m * 16 + fr) * 32 + fk];
#pragma unroll
    for (int n = 0; n < 4; ++n)
      bf[n] = *(const half8_t*)&Bs[(wc * 64 + n * 16 + fr) * 32 + fk];
#pragma unroll
    for (int m = 0; m < 4; ++m)
#pragma unroll
      for (int n = 0; n < 4; ++n)
        acc[m][n] = __builtin_amdgcn_mfma_f32_16x16x32_f16(af[m], bf[n],
                                                           acc[m][n], 0, 0, 0);
    __syncthreads();
  }

  const int crow = m0 + wr * 64 + ((lane >> 4) << 2);
  const int ccol = n0 + wc * 64 + (lane & 15);
#pragma unroll
  for (int m = 0; m < 4; ++m)
#pragma unroll
    for (int n = 0; n < 4; ++n) {
      const int col = ccol + n * 16;
#pragma unroll
      for (int r = 0; r < 4; ++r) {
        const int row = crow + m * 16 + r;
        const float v = acc[m][n][r];
        if (MODE == 0) {
          C[(size_t)row * N + col] = v;
        } else if (MODE == 1) {
          size_t idx = (size_t)row * N + col;
          out[idx] = (v + bias[col]) * (float)mulh[idx];
        } else {
          float g = v + part[(size_t)(row >> 5) * NG + col];
          if (col < 1024)
            igb[(size_t)row * HD + col] = (_Float16)sigmoidf_(g);
          else if (col < 2048)
            out[(size_t)row * HD + (col - 1024)] = sigmoidf_(g);
          else
            th[(size_t)row * HD + (col - 2048)] = (_Float16)tanhf_(g);
        }
      }
    }
}

// ---------------- launch ----------------
extern "C" void kernel_launch(void* const* d_in, const int* in_sizes, int n_in,
                              void* d_out, int out_size, void* d_ws, size_t ws_size,
                              hipStream_t stream) {
  const float* x  = (const float*)d_in[0];
  const float* W1 = (const float*)d_in[1];
  const float* b1 = (const float*)d_in[2];
  const float* W2 = (const float*)d_in[3];
  const float* b2 = (const float*)d_in[4];
  float* out0 = (float*)d_out;                          // fg [4096][1024] f32
  float* out1 = out0 + (size_t)S_SEQ * HD;              // hr [4096][1024] f32

  char* ws = (char*)d_ws;
  _Float16* Ah    = (_Float16*)(ws);                        // 16 MiB [4096][2048]
  _Float16* w1h   = (_Float16*)(ws + ((size_t)16 << 20));   // 12 MiB [3072][2048]
  _Float16* w2h   = (_Float16*)(ws + ((size_t)28 << 20));   //  2 MiB [1024][1024]
  _Float16* xsumh = (_Float16*)(ws + ((size_t)30 << 20));   // .25MiB [128][1024]
  float*    praw  = (float*)   (ws + ((size_t)31 << 20));   // 1.5MiB [128][3072]
  float*    pout  = (float*)   (ws + ((size_t)33 << 20));   // 1.5MiB [128][3072]
  _Float16* igb   = (_Float16*)(ws + ((size_t)35 << 20));   //  8 MiB [4096][1024]
  _Float16* th    = (_Float16*)(ws + ((size_t)43 << 20));   //  8 MiB [4096][1024]

  // weight conversions (flat, no reorder needed)
  conv_f32_f16<<<dim3(6144), dim3(256), 0, stream>>>(W1, w1h, NG * 2048 / 4);
  conv_f32_f16<<<dim3(1024), dim3(256), 0, stream>>>(W2, w2h, HD * HD / 4);

  // x -> [x | s_local] fp16 + chunk sums
  scan_x<<<dim3(4, NCH), dim3(256), 0, stream>>>(x, Ah, xsumh);

  // part_raw[c][j] = xsum[c] @ W1b_j^T   (B = W1 rows, cols 1024..2047)
  gemm_bt<0><<<dim3(NG / 128, 1), dim3(256), 0, stream>>>(
      xsumh, w1h + 1024, NCH, NG, HD, 2048,
      praw, nullptr, nullptr, nullptr, nullptr, nullptr, nullptr);

  // exclusive chunk scan + b1
  scan_part<<<dim3(NG / 256), dim3(256), 0, stream>>>(praw, b1, pout);

  // GEMM1: gates = [x|s_loc] @ W1^T + part ; fused activations
  gemm_bt<2><<<dim3(NG / 128, S_SEQ / 128), dim3(256), 0, stream>>>(
      Ah, w1h, S_SEQ, NG, 2048, 2048,
      nullptr, nullptr, nullptr, out0, pout, igb, th);

  // GEMM2: hr = (tanh(h) @ W2^T + b2) * ig
  gemm_bt<1><<<dim3(HD / 128, S_SEQ / 128), dim3(256), 0, stream>>>(
      th, w2h, S_SEQ, HD, HD, HD,
      nullptr, b2, igb, out1, nullptr, nullptr, nullptr);
}